// Round 7
// baseline (159.746 us; speedup 1.0000x reference)
//
#include <hip/hip_runtime.h>
#include <hip/hip_bf16.h>
#include <math.h>

#define HDIM 512
#define ADIM 512
#define BATCH 32
#define TDIM 32
#define KDIM 196
#define MROWS 8320            // 6272 (att) + 1024 (hid) + 1024 (sen)
#define ZSC 2.885390081777927f   // 2*log2(e): exp2(ZSC*u) = exp(2u)

typedef short short8 __attribute__((ext_vector_type(8)));
typedef float floatx4 __attribute__((ext_vector_type(4)));

// ---------------------------------------------------------------------------
// async global->LDS 16B copy (global_load_lds_dwordx4)
// ---------------------------------------------------------------------------
__device__ __forceinline__ void gl_lds16(const __hip_bfloat16* g, __hip_bfloat16* l) {
    __builtin_amdgcn_global_load_lds(
        (const __attribute__((address_space(1))) unsigned int*)(const void*)g,
        (__attribute__((address_space(3))) unsigned int*)(void*)l, 16, 0, 0);
}

// tanh(u') where u' = ZSC*u is pre-scaled: tanh = 1 - 2*rcp(exp2(u')+1)
__device__ __forceinline__ float tanh_ps(float up) {
    float e = __builtin_amdgcn_exp2f(up);
    float r = __builtin_amdgcn_rcpf(e + 1.0f);
    return fmaf(-2.0f, r, 1.0f);
}

// ---------------------------------------------------------------------------
// convB: W[k][n] fp32 -> transposed bf16 hi/lo [3][n=512][k=512]. 192 blocks.
// ---------------------------------------------------------------------------
__global__ __launch_bounds__(256) void convB(const float* __restrict__ Wv,
                                             const float* __restrict__ Wg,
                                             const float* __restrict__ Ws,
                                             __hip_bfloat16* __restrict__ bthi,
                                             __hip_bfloat16* __restrict__ btlo) {
    __shared__ float tile[64][65];
    const int tid = threadIdx.x;
    const int bid = blockIdx.x;                // 0..191
    const int mz  = bid >> 6;                  // 0..2
    const int rem = bid & 63;
    const int k0  = (rem >> 3) * 64;
    const int n0  = (rem & 7) * 64;
    const float* src = mz == 0 ? Wv : (mz == 1 ? Wg : Ws);
    #pragma unroll
    for (int i = 0; i < 16; ++i) {
        int k = (tid >> 6) * 16 + i;
        int n = tid & 63;
        tile[k][n] = src[(size_t)(k0 + k) * 512 + n0 + n];
    }
    __syncthreads();
    const size_t obase = (size_t)mz * 262144;
    #pragma unroll
    for (int i = 0; i < 16; ++i) {
        int n = (tid >> 6) * 16 + i;
        int k = tid & 63;
        float x = tile[k][n];
        __hip_bfloat16 h = __float2bfloat16(x);
        __hip_bfloat16 l = __float2bfloat16(x - __bfloat162float(h));
        size_t o = obase + (size_t)(n0 + n) * 512 + k0 + k;
        bthi[o] = h;
        btlo[o] = l;
    }
}

// ---------------------------------------------------------------------------
// split-bf16 MFMA GEMM (bf16x3), A-conversion fused, BK=64:
// C[8320 x 512] = ZSC * [att|hid|sen] @ [Wv|Wg|Ws]
// 8 K-iters (half the barrier drains of BK=32); 48 MFMA per wave per barrier.
// LDS 48 KB -> 3 blocks/CU. Tile 64(M) x 128(N); 4 waves 2x2, wave = 32x64.
// grid (130, 4).
// ---------------------------------------------------------------------------
#define AHI 0
#define ALO 4096
#define BHI 8192
#define BLO 16384
__global__ __launch_bounds__(256) void gemm_bf16x3(
        const float* __restrict__ att, const float* __restrict__ hid,
        const float* __restrict__ sen,
        const __hip_bfloat16* __restrict__ Bthi, const __hip_bfloat16* __restrict__ Btlo,
        float* __restrict__ C) {
    __shared__ __hip_bfloat16 smem[24576];   // 48 KB

    const int tid  = threadIdx.x;
    const int lane = tid & 63;
    const int wave = tid >> 6;
    const int wm = wave >> 1;
    const int wn = wave & 1;
    const int row0 = blockIdx.x * 64;
    const int col0 = blockIdx.y * 128;
    const int seg = (row0 < 6272) ? 0 : ((row0 < 7296) ? 1 : 2);
    const float* Asrc = seg == 0 ? att : (seg == 1 ? hid : sen);
    const int arow0 = row0 - (seg == 0 ? 0 : (seg == 1 ? 6272 : 7296));
    const __hip_bfloat16* Bh = Bthi + (size_t)seg * 262144;
    const __hip_bfloat16* Bl = Btlo + (size_t)seg * 262144;

    floatx4 acc[2][4];
    #pragma unroll
    for (int i = 0; i < 2; ++i)
        #pragma unroll
        for (int j = 0; j < 4; ++j)
            acc[i][j] = (floatx4){0.f, 0.f, 0.f, 0.f};

    const int kq8   = (lane >> 4) << 3;
    const int a_row = tid >> 2;            // 0..63
    const int a_ks  = (tid & 3) << 4;      // 0,16,32,48

    for (int k0 = 0; k0 < 512; k0 += 64) {
        // ---- B staging: 128n x 64k hi+lo = 2048 16B units, 8/thread ----
        #pragma unroll
        for (int s = 0; s < 4; ++s) {
            int u = tid + (s << 8);                    // 0..1023
            int n = u >> 3, koff = (u & 7) << 3;
            gl_lds16(Bh + (size_t)(col0 + n) * 512 + k0 + koff, smem + BHI + u * 8);
            gl_lds16(Bl + (size_t)(col0 + n) * 512 + k0 + koff, smem + BLO + u * 8);
        }
        // ---- A staging: 64 rows x 64 k fp32 -> hi/lo; 16 elems/thread ----
        {
            const float* ap = Asrc + (size_t)(arow0 + a_row) * 512 + k0 + a_ks;
            float4 v0 = *(const float4*)ap;
            float4 v1 = *(const float4*)(ap + 4);
            float4 v2 = *(const float4*)(ap + 8);
            float4 v3 = *(const float4*)(ap + 12);
            float x[16] = {v0.x, v0.y, v0.z, v0.w, v1.x, v1.y, v1.z, v1.w,
                           v2.x, v2.y, v2.z, v2.w, v3.x, v3.y, v3.z, v3.w};
            union { __hip_bfloat16 h[16]; short8 v[2]; } Hi, Lo;
            #pragma unroll
            for (int i = 0; i < 16; ++i) {
                Hi.h[i] = __float2bfloat16(x[i]);
                Lo.h[i] = __float2bfloat16(x[i] - __bfloat162float(Hi.h[i]));
            }
            *(short8*)(smem + AHI + a_row * 64 + a_ks)     = Hi.v[0];
            *(short8*)(smem + AHI + a_row * 64 + a_ks + 8) = Hi.v[1];
            *(short8*)(smem + ALO + a_row * 64 + a_ks)     = Lo.v[0];
            *(short8*)(smem + ALO + a_row * 64 + a_ks + 8) = Lo.v[1];
        }
        asm volatile("s_waitcnt vmcnt(0)" ::: "memory");
        __syncthreads();

        // ---- two K=32 sub-steps ----
        #pragma unroll
        for (int kk = 0; kk < 64; kk += 32) {
            const int kf = kk + kq8;
            short8 a_hi[2], a_lo[2], b_hi[4], b_lo[4];
            #pragma unroll
            for (int i = 0; i < 2; ++i) {
                int m = wm * 32 + i * 16 + (lane & 15);
                a_hi[i] = *(const short8*)(smem + AHI + m * 64 + kf);
                a_lo[i] = *(const short8*)(smem + ALO + m * 64 + kf);
            }
            #pragma unroll
            for (int j = 0; j < 4; ++j) {
                int n = wn * 64 + j * 16 + (lane & 15);
                b_hi[j] = *(const short8*)(smem + BHI + n * 64 + kf);
                b_lo[j] = *(const short8*)(smem + BLO + n * 64 + kf);
            }
            #pragma unroll
            for (int i = 0; i < 2; ++i)
                #pragma unroll
                for (int j = 0; j < 4; ++j) {
                    acc[i][j] = __builtin_amdgcn_mfma_f32_16x16x32_bf16(a_hi[i], b_hi[j], acc[i][j], 0, 0, 0);
                    acc[i][j] = __builtin_amdgcn_mfma_f32_16x16x32_bf16(a_hi[i], b_lo[j], acc[i][j], 0, 0, 0);
                    acc[i][j] = __builtin_amdgcn_mfma_f32_16x16x32_bf16(a_lo[i], b_hi[j], acc[i][j], 0, 0, 0);
                }
        }
        __syncthreads();
    }

    // ---- epilogue: C/D layout col=lane&15, row=(lane>>4)*4+r; pre-scale ZSC ----
    #pragma unroll
    for (int i = 0; i < 2; ++i) {
        #pragma unroll
        for (int r = 0; r < 4; ++r) {
            int row = row0 + wm * 32 + i * 16 + ((lane >> 4) << 2) + r;
            float* cp = C + (size_t)row * 512 + col0 + wn * 64 + (lane & 15);
            #pragma unroll
            for (int j = 0; j < 4; ++j) cp[j * 16] = acc[i][j][r] * ZSC;
        }
    }
}

// ---------------------------------------------------------------------------
// z kernel v5 — lane owns one (t,k); no shuffles. Inner: add, exp2, add1,
// rcp, fma, fma (2 trans). cv/cg arrive pre-scaled by ZSC. LDS 21.6 KB.
// Grid (25 kb, 32 b), 256 threads.
// ---------------------------------------------------------------------------
__global__ __launch_bounds__(256) void z_kernel(const float* __restrict__ cv,
                                                const float* __restrict__ cg,
                                                const float* __restrict__ wh,
                                                float* __restrict__ z_t) {
    __shared__ float cvs[8][132];    // +4 pad keeps rows 16B-aligned
    __shared__ float cgs[32][132];
    __shared__ float whs[132];

    const int kb  = blockIdx.x;          // 0..24
    const int b   = blockIdx.y;
    const int tid = threadIdx.x;
    const int t       = tid & 31;
    const int k_local = tid >> 5;        // 0..7
    const int k       = kb * 8 + k_local;
    const bool do_z = (k < KDIM);

    const int r_st = tid >> 5;
    const int q_st = tid & 31;

    float acc = 0.f, acc2 = 0.f;

    for (int c = 0; c < 4; ++c) {
        const int a0 = c * 128;
        __syncthreads();
        {
            int kr = kb * 8 + r_st;
            if (kr < KDIM)
                *(float4*)&cvs[r_st][4 * q_st] =
                    *(const float4*)(cv + ((size_t)b * KDIM + kr) * ADIM + a0 + 4 * q_st);
        }
        #pragma unroll
        for (int s = 0; s < 4; ++s) {
            int idx = tid + s * 256;
            int rr = idx >> 5, qq = idx & 31;
            *(float4*)&cgs[rr][4 * qq] =
                *(const float4*)(cg + ((size_t)b * TDIM + rr) * ADIM + a0 + 4 * qq);
        }
        if (tid < 32)
            *(float4*)&whs[4 * tid] = *(const float4*)(wh + a0 + 4 * tid);
        __syncthreads();

        if (do_z) {
            #pragma unroll 8
            for (int q = 0; q < 32; ++q) {
                float4 v  = *(const float4*)&cvs[k_local][4 * q];
                float4 g  = *(const float4*)&cgs[t][4 * q];
                float4 w4 = *(const float4*)&whs[4 * q];
                acc  = fmaf(w4.x, tanh_ps(v.x + g.x), acc);
                acc2 = fmaf(w4.y, tanh_ps(v.y + g.y), acc2);
                acc  = fmaf(w4.z, tanh_ps(v.z + g.z), acc);
                acc2 = fmaf(w4.w, tanh_ps(v.w + g.w), acc2);
            }
        }
    }

    if (do_z) z_t[((size_t)b * TDIM + t) * KDIM + k] = acc + acc2;
}

// ---------------------------------------------------------------------------
// out kernel v4: grid (8 tg, 32 b, 2 hs); wave w owns t = tg*4+w.
// z_ext + softmax computed in both h-halves (cheap); alpha/beta written by
// hs==0 only. Each thread covers one h = hs*256+tid -> 2x blocks vs v3 for
// latency hiding on the 196-iter att-load loop.
// ---------------------------------------------------------------------------
__global__ __launch_bounds__(256) void out_kernel(const float* __restrict__ z_t,
                                                  const float* __restrict__ cs,
                                                  const float* __restrict__ cg,
                                                  const float* __restrict__ wh,
                                                  const float* __restrict__ att,
                                                  const float* __restrict__ sen,
                                                  float* __restrict__ out_chat,
                                                  float* __restrict__ out_alpha,
                                                  float* __restrict__ out_beta) {
    __shared__ float alpha_s[4][200];
    __shared__ float beta_s[4];

    const int tg = blockIdx.x;      // 0..7
    const int b  = blockIdx.y;
    const int hs = blockIdx.z;      // 0..1
    const int tid  = threadIdx.x;
    const int wave = tid >> 6;
    const int lane = tid & 63;
    const int t = tg * 4 + wave;
    const int h = hs * 256 + tid;

    // ---- z_ext: lane covers a = 8*lane .. 8*lane+7 ----
    const float* csrow = cs + ((size_t)b * TDIM + t) * ADIM;
    const float* cgrow = cg + ((size_t)b * TDIM + t) * ADIM;
    float p = 0.f;
    #pragma unroll
    for (int hh = 0; hh < 2; ++hh) {
        float4 sv = *(const float4*)(csrow + 8 * lane + 4 * hh);
        float4 gv = *(const float4*)(cgrow + 8 * lane + 4 * hh);
        float4 w4 = *(const float4*)(wh + 8 * lane + 4 * hh);
        p = fmaf(w4.x, tanh_ps(sv.x + gv.x), p);
        p = fmaf(w4.y, tanh_ps(sv.y + gv.y), p);
        p = fmaf(w4.z, tanh_ps(sv.z + gv.z), p);
        p = fmaf(w4.w, tanh_ps(sv.w + gv.w), p);
    }
    #pragma unroll
    for (int off = 32; off; off >>= 1) p += __shfl_xor(p, off, 64);
    const float se = p;

    // ---- softmax over k ----
    const float* zrow = z_t + ((size_t)b * TDIM + t) * KDIM;
    float z0 = zrow[lane];
    float z1 = zrow[lane + 64];
    float z2 = zrow[lane + 128];
    float z3 = (lane < 4) ? zrow[lane + 192] : -INFINITY;

    float m = fmaxf(fmaxf(z0, z1), fmaxf(z2, z3));
    #pragma unroll
    for (int off = 32; off; off >>= 1) m = fmaxf(m, __shfl_xor(m, off, 64));

    float e0 = __expf(z0 - m), e1 = __expf(z1 - m);
    float e2 = __expf(z2 - m), e3 = (lane < 4) ? __expf(z3 - m) : 0.0f;
    float s = e0 + e1 + e2 + e3;
    #pragma unroll
    for (int off = 32; off; off >>= 1) s += __shfl_xor(s, off, 64);

    float invS = 1.0f / s;
    float a0 = e0 * invS, a1 = e1 * invS, a2 = e2 * invS, a3 = e3 * invS;

    alpha_s[wave][lane] = a0;
    alpha_s[wave][lane + 64] = a1;
    alpha_s[wave][lane + 128] = a2;
    if (lane < 4) alpha_s[wave][lane + 192] = a3;
    if (hs == 0) {
        float* arow = out_alpha + ((size_t)b * TDIM + t) * KDIM;
        arow[lane] = a0;
        arow[lane + 64] = a1;
        arow[lane + 128] = a2;
        if (lane < 4) arow[lane + 192] = a3;
    }

    float m2 = fmaxf(m, se);
    float eext = __expf(se - m2);
    float S2 = s * __expf(m - m2) + eext;
    float beta = eext / S2;
    if (lane == 0) {
        beta_s[wave] = beta;
        if (hs == 0) out_beta[b * TDIM + t] = beta;
    }
    __syncthreads();

    // ---- c_t for 4 t's: thread covers one h ----
    const float* attb = att + (size_t)b * KDIM * HDIM;
    float acc[4] = {};
    #pragma unroll 8
    for (int k = 0; k < KDIM; ++k) {
        float av = attb[(size_t)k * HDIM + h];
        #pragma unroll
        for (int w = 0; w < 4; ++w)
            acc[w] = fmaf(alpha_s[w][k], av, acc[w]);
    }

    #pragma unroll
    for (int w = 0; w < 4; ++w) {
        int tt = tg * 4 + w;
        float bt = beta_s[w];
        float om = 1.0f - bt;
        size_t o = ((size_t)b * TDIM + tt) * HDIM;
        out_chat[o + h] = fmaf(bt, sen[o + h], om * acc[w]);
    }
}

// ---------------------------------------------------------------------------
// fallback fp32 tiled GEMM (only if workspace too small for bf16 path);
// writes C pre-scaled by ZSC.
// ---------------------------------------------------------------------------
__global__ __launch_bounds__(256) void gemm_f32(const float* __restrict__ Amat,
                                                const float* __restrict__ Bmat,
                                                float* __restrict__ Cmat) {
    __shared__ float As[16][64 + 4];
    __shared__ float Bs[16][64];
    const int tid = threadIdx.x;
    const int tx = tid & 15;
    const int ty = tid >> 4;
    const int row0 = blockIdx.x * 64;
    const int col0 = blockIdx.y * 64;
    float acc[4][4] = {};
    for (int k0 = 0; k0 < HDIM; k0 += 16) {
        #pragma unroll
        for (int i = 0; i < 4; ++i) {
            int idx = tid + i * 256;
            As[idx & 15][idx >> 4] = Amat[(size_t)(row0 + (idx >> 4)) * HDIM + k0 + (idx & 15)];
        }
        #pragma unroll
        for (int i = 0; i < 4; ++i) {
            int idx = tid + i * 256;
            Bs[idx >> 6][idx & 63] = Bmat[(size_t)(k0 + (idx >> 6)) * ADIM + col0 + (idx & 63)];
        }
        __syncthreads();
        #pragma unroll
        for (int k = 0; k < 16; ++k) {
            float4 a4 = *(const float4*)&As[k][ty * 4];
            float4 b4 = *(const float4*)&Bs[k][tx * 4];
            float a[4] = {a4.x, a4.y, a4.z, a4.w};
            float b[4] = {b4.x, b4.y, b4.z, b4.w};
            #pragma unroll
            for (int i = 0; i < 4; ++i)
                #pragma unroll
                for (int j = 0; j < 4; ++j)
                    acc[i][j] += a[i] * b[j];
        }
        __syncthreads();
    }
    #pragma unroll
    for (int i = 0; i < 4; ++i) {
        size_t r = (size_t)(row0 + ty * 4 + i) * ADIM + col0 + tx * 4;
        #pragma unroll
        for (int j = 0; j < 4; ++j) Cmat[r + j] = acc[i][j] * ZSC;
    }
}

// ---------------------------------------------------------------------------
extern "C" void kernel_launch(void* const* d_in, const int* in_sizes, int n_in,
                              void* d_out, int out_size, void* d_ws, size_t ws_size,
                              hipStream_t stream) {
    const float* att = (const float*)d_in[0];
    const float* hid = (const float*)d_in[1];
    const float* sen = (const float*)d_in[2];
    const float* Wv  = (const float*)d_in[3];
    const float* Wg  = (const float*)d_in[4];
    const float* Ws  = (const float*)d_in[5];
    const float* wh  = (const float*)d_in[6];

    float* out = (float*)d_out;
    float* out_chat  = out;
    float* out_alpha = out + 524288;
    float* out_beta  = out + 524288 + 200704;

    char* wsb = (char*)d_ws;
    const size_t C_BYTES  = (size_t)MROWS * 512 * 4;   // 17,039,360
    const size_t ZT_BYTES = 200704 * 4;
    const size_t BT_BYTES = (size_t)3 * 512 * 512 * 2; // 1,572,864
    const size_t need = C_BYTES + ZT_BYTES + 2 * BT_BYTES;

    float* C  = (float*)wsb;
    float* cv = C;                         // rows [0, 6272)
    float* cg = C + 6272 * 512;            // rows [6272, 7296)
    float* cs = C + 7296 * 512;            // rows [7296, 8320)
    float* zt = (float*)(wsb + C_BYTES);

    if (ws_size >= need) {
        __hip_bfloat16* bthi = (__hip_bfloat16*)(wsb + C_BYTES + ZT_BYTES);
        __hip_bfloat16* btlo = bthi + (size_t)3 * 512 * 512;

        convB<<<192, 256, 0, stream>>>(Wv, Wg, Ws, bthi, btlo);
        gemm_bf16x3<<<dim3(130, 4), 256, 0, stream>>>(att, hid, sen, bthi, btlo, C);
    } else {
        gemm_f32<<<dim3(98, 8), 256, 0, stream>>>(att, Wv, cv);
        gemm_f32<<<dim3(16, 8), 256, 0, stream>>>(hid, Wg, cg);
        gemm_f32<<<dim3(16, 8), 256, 0, stream>>>(sen, Ws, cs);
    }

    z_kernel<<<dim3(25, 32), 256, 0, stream>>>(cv, cg, wh, zt);

    out_kernel<<<dim3(8, 32, 2), 256, 0, stream>>>(zt, cs, cg, wh, att, sen,
                                                   out_chat, out_alpha, out_beta);
}

// Round 8
// 146.267 us; speedup vs baseline: 1.0922x; 1.0922x over previous
//
#include <hip/hip_runtime.h>
#include <hip/hip_bf16.h>
#include <math.h>

#define HDIM 512
#define ADIM 512
#define BATCH 32
#define TDIM 32
#define KDIM 196
#define MROWS 8320            // 6272 (att) + 1024 (hid) + 1024 (sen)
#define ZSC 2.885390081777927f   // 2*log2(e): exp2(ZSC*u) = exp(2u)
#define ZT_N 200704              // 32*32*196

typedef short short8 __attribute__((ext_vector_type(8)));
typedef float floatx4 __attribute__((ext_vector_type(4)));

// ---------------------------------------------------------------------------
// async global->LDS 16B copy (global_load_lds_dwordx4)
// ---------------------------------------------------------------------------
__device__ __forceinline__ void gl_lds16(const __hip_bfloat16* g, __hip_bfloat16* l) {
    __builtin_amdgcn_global_load_lds(
        (const __attribute__((address_space(1))) unsigned int*)(const void*)g,
        (__attribute__((address_space(3))) unsigned int*)(void*)l, 16, 0, 0);
}

// tanh(u') where u' = ZSC*u is pre-scaled: tanh = 1 - 2*rcp(exp2(u')+1)
__device__ __forceinline__ float tanh_ps(float up) {
    float e = __builtin_amdgcn_exp2f(up);
    float r = __builtin_amdgcn_rcpf(e + 1.0f);
    return fmaf(-2.0f, r, 1.0f);
}

// ---------------------------------------------------------------------------
// convB: W[k][n] fp32 -> transposed bf16 hi/lo [3][n=512][k=512]. 192 blocks.
// ---------------------------------------------------------------------------
__global__ __launch_bounds__(256) void convB(const float* __restrict__ Wv,
                                             const float* __restrict__ Wg,
                                             const float* __restrict__ Ws,
                                             __hip_bfloat16* __restrict__ bthi,
                                             __hip_bfloat16* __restrict__ btlo) {
    __shared__ float tile[64][65];
    const int tid = threadIdx.x;
    const int bid = blockIdx.x;                // 0..191
    const int mz  = bid >> 6;                  // 0..2
    const int rem = bid & 63;
    const int k0  = (rem >> 3) * 64;
    const int n0  = (rem & 7) * 64;
    const float* src = mz == 0 ? Wv : (mz == 1 ? Wg : Ws);
    #pragma unroll
    for (int i = 0; i < 16; ++i) {
        int k = (tid >> 6) * 16 + i;
        int n = tid & 63;
        tile[k][n] = src[(size_t)(k0 + k) * 512 + n0 + n];
    }
    __syncthreads();
    const size_t obase = (size_t)mz * 262144;
    #pragma unroll
    for (int i = 0; i < 16; ++i) {
        int n = (tid >> 6) * 16 + i;
        int k = tid & 63;
        float x = tile[k][n];
        __hip_bfloat16 h = __float2bfloat16(x);
        __hip_bfloat16 l = __float2bfloat16(x - __bfloat162float(h));
        size_t o = obase + (size_t)(n0 + n) * 512 + k0 + k;
        bthi[o] = h;
        btlo[o] = l;
    }
}

// ---------------------------------------------------------------------------
// split-bf16 MFMA GEMM (bf16x3), A-conversion fused, BK=32 (round-6 proven):
// C[8320 x 512] = ZSC * [att|hid|sen] @ [Wv|Wg|Ws]
// Tile 64(M) x 128(N); 4 waves 2x2, wave = 32x64. grid (130, 4). LDS 24 KB.
// ---------------------------------------------------------------------------
__global__ __launch_bounds__(256) void gemm_bf16x3(
        const float* __restrict__ att, const float* __restrict__ hid,
        const float* __restrict__ sen,
        const __hip_bfloat16* __restrict__ Bthi, const __hip_bfloat16* __restrict__ Btlo,
        float* __restrict__ C) {
    // LDS (bf16 elems): sAhi[64][32] @0, sAlo @2048, sBhi[128][32] @4096, sBlo @8192
    __shared__ __hip_bfloat16 smem[12288];

    const int tid  = threadIdx.x;
    const int lane = tid & 63;
    const int wave = tid >> 6;
    const int wm = wave >> 1;
    const int wn = wave & 1;
    const int row0 = blockIdx.x * 64;
    const int col0 = blockIdx.y * 128;
    const int seg = (row0 < 6272) ? 0 : ((row0 < 7296) ? 1 : 2);
    const float* Asrc = seg == 0 ? att : (seg == 1 ? hid : sen);
    const int arow0 = row0 - (seg == 0 ? 0 : (seg == 1 ? 6272 : 7296));
    const __hip_bfloat16* Bh = Bthi + (size_t)seg * 262144;
    const __hip_bfloat16* Bl = Btlo + (size_t)seg * 262144;

    floatx4 acc[2][4];
    #pragma unroll
    for (int i = 0; i < 2; ++i)
        #pragma unroll
        for (int j = 0; j < 4; ++j)
            acc[i][j] = (floatx4){0.f, 0.f, 0.f, 0.f};

    const int kq8 = (lane >> 4) << 3;
    const int a_row = tid >> 2;          // 0..63
    const int a_k   = (tid & 3) << 3;    // 0,8,16,24

    for (int k0 = 0; k0 < 512; k0 += 32) {
        // ---- B staging (async) : 1024 16B units ----
        #pragma unroll
        for (int s = 0; s < 4; ++s) {
            int u = tid + (s << 8);                    // 0..1023
            if (u < 512) {
                gl_lds16(Bh + (size_t)(col0 + (u >> 2)) * 512 + k0 + ((u & 3) << 3),
                         smem + 4096 + u * 8);
            } else {
                int v = u - 512;
                gl_lds16(Bl + (size_t)(col0 + (v >> 2)) * 512 + k0 + ((v & 3) << 3),
                         smem + 8192 + v * 8);
            }
        }
        // ---- A staging: 8 fp32/thread -> bf16 hi/lo -> ds_write_b128 ----
        {
            const float* ap = Asrc + (size_t)(arow0 + a_row) * 512 + k0 + a_k;
            float4 v0 = *(const float4*)ap;
            float4 v1 = *(const float4*)(ap + 4);
            float x[8] = {v0.x, v0.y, v0.z, v0.w, v1.x, v1.y, v1.z, v1.w};
            union { __hip_bfloat16 h[8]; short8 v; } Hi, Lo;
            #pragma unroll
            for (int i = 0; i < 8; ++i) {
                Hi.h[i] = __float2bfloat16(x[i]);
                Lo.h[i] = __float2bfloat16(x[i] - __bfloat162float(Hi.h[i]));
            }
            *(short8*)(smem + a_row * 32 + a_k)        = Hi.v;
            *(short8*)(smem + 2048 + a_row * 32 + a_k) = Lo.v;
        }
        asm volatile("s_waitcnt vmcnt(0)" ::: "memory");
        __syncthreads();

        // ---- fragments ----
        short8 a_hi[2], a_lo[2], b_hi[4], b_lo[4];
        #pragma unroll
        for (int i = 0; i < 2; ++i) {
            int m = wm * 32 + i * 16 + (lane & 15);
            a_hi[i] = *(const short8*)(smem + m * 32 + kq8);
            a_lo[i] = *(const short8*)(smem + 2048 + m * 32 + kq8);
        }
        #pragma unroll
        for (int j = 0; j < 4; ++j) {
            int n = wn * 64 + j * 16 + (lane & 15);
            b_hi[j] = *(const short8*)(smem + 4096 + n * 32 + kq8);
            b_lo[j] = *(const short8*)(smem + 8192 + n * 32 + kq8);
        }

        // ---- 3-product split MFMA ----
        #pragma unroll
        for (int i = 0; i < 2; ++i)
            #pragma unroll
            for (int j = 0; j < 4; ++j) {
                acc[i][j] = __builtin_amdgcn_mfma_f32_16x16x32_bf16(a_hi[i], b_hi[j], acc[i][j], 0, 0, 0);
                acc[i][j] = __builtin_amdgcn_mfma_f32_16x16x32_bf16(a_hi[i], b_lo[j], acc[i][j], 0, 0, 0);
                acc[i][j] = __builtin_amdgcn_mfma_f32_16x16x32_bf16(a_lo[i], b_hi[j], acc[i][j], 0, 0, 0);
            }
        __syncthreads();
    }

    // ---- epilogue: C/D layout col=lane&15, row=(lane>>4)*4+r; pre-scale ZSC ----
    #pragma unroll
    for (int i = 0; i < 2; ++i) {
        #pragma unroll
        for (int r = 0; r < 4; ++r) {
            int row = row0 + wm * 32 + i * 16 + ((lane >> 4) << 2) + r;
            float* cp = C + (size_t)row * 512 + col0 + wn * 64 + (lane & 15);
            #pragma unroll
            for (int j = 0; j < 4; ++j) cp[j * 16] = acc[i][j][r] * ZSC;
        }
    }
}

// ---------------------------------------------------------------------------
// z kernel v6 — a-split for occupancy: grid (25 kb, 32 b, 2 ha). Each block
// reduces 256 of 512 a-dims into z_part[ha]; out_kernel sums the partials.
// 1600 blocks = ~6.2 waves/SIMD to saturate the ~16cyc transcendental pipe.
// Lane owns one (t,k); inner: add, exp2, add1, rcp, fma, fma. LDS 21.6 KB.
// ---------------------------------------------------------------------------
__global__ __launch_bounds__(256) void z_kernel(const float* __restrict__ cv,
                                                const float* __restrict__ cg,
                                                const float* __restrict__ wh,
                                                float* __restrict__ z_part) {
    __shared__ float cvs[8][132];    // +4 pad keeps rows 16B-aligned
    __shared__ float cgs[32][132];
    __shared__ float whs[132];

    const int kb  = blockIdx.x;          // 0..24
    const int b   = blockIdx.y;
    const int ha  = blockIdx.z;          // 0..1 (a-half)
    const int tid = threadIdx.x;
    const int t       = tid & 31;
    const int k_local = tid >> 5;        // 0..7
    const int k       = kb * 8 + k_local;
    const bool do_z = (k < KDIM);

    const int r_st = tid >> 5;
    const int q_st = tid & 31;

    float acc = 0.f, acc2 = 0.f;

    for (int c = 0; c < 2; ++c) {
        const int a0 = (ha * 2 + c) * 128;
        __syncthreads();
        {
            int kr = kb * 8 + r_st;
            if (kr < KDIM)
                *(float4*)&cvs[r_st][4 * q_st] =
                    *(const float4*)(cv + ((size_t)b * KDIM + kr) * ADIM + a0 + 4 * q_st);
        }
        #pragma unroll
        for (int s = 0; s < 4; ++s) {
            int idx = tid + s * 256;
            int rr = idx >> 5, qq = idx & 31;
            *(float4*)&cgs[rr][4 * qq] =
                *(const float4*)(cg + ((size_t)b * TDIM + rr) * ADIM + a0 + 4 * qq);
        }
        if (tid < 32)
            *(float4*)&whs[4 * tid] = *(const float4*)(wh + a0 + 4 * tid);
        __syncthreads();

        if (do_z) {
            #pragma unroll 8
            for (int q = 0; q < 32; ++q) {
                float4 v  = *(const float4*)&cvs[k_local][4 * q];
                float4 g  = *(const float4*)&cgs[t][4 * q];
                float4 w4 = *(const float4*)&whs[4 * q];
                acc  = fmaf(w4.x, tanh_ps(v.x + g.x), acc);
                acc2 = fmaf(w4.y, tanh_ps(v.y + g.y), acc2);
                acc  = fmaf(w4.z, tanh_ps(v.z + g.z), acc);
                acc2 = fmaf(w4.w, tanh_ps(v.w + g.w), acc2);
            }
        }
    }

    if (do_z)
        z_part[(size_t)ha * ZT_N + ((size_t)b * TDIM + t) * KDIM + k] = acc + acc2;
}

// ---------------------------------------------------------------------------
// out kernel v5: grid (8 tg, 32 b, 2 hs); wave w owns t = tg*4+w.
// Sums the two z partials, z_ext in-register, softmax, beta, c_t, blend.
// alpha/beta written by hs==0 only.
// ---------------------------------------------------------------------------
__global__ __launch_bounds__(256) void out_kernel(const float* __restrict__ z_part,
                                                  const float* __restrict__ cs,
                                                  const float* __restrict__ cg,
                                                  const float* __restrict__ wh,
                                                  const float* __restrict__ att,
                                                  const float* __restrict__ sen,
                                                  float* __restrict__ out_chat,
                                                  float* __restrict__ out_alpha,
                                                  float* __restrict__ out_beta) {
    __shared__ float alpha_s[4][200];
    __shared__ float beta_s[4];

    const int tg = blockIdx.x;      // 0..7
    const int b  = blockIdx.y;
    const int hs = blockIdx.z;      // 0..1
    const int tid  = threadIdx.x;
    const int wave = tid >> 6;
    const int lane = tid & 63;
    const int t = tg * 4 + wave;
    const int h = hs * 256 + tid;

    // ---- z_ext: lane covers a = 8*lane .. 8*lane+7 ----
    const float* csrow = cs + ((size_t)b * TDIM + t) * ADIM;
    const float* cgrow = cg + ((size_t)b * TDIM + t) * ADIM;
    float p = 0.f;
    #pragma unroll
    for (int hh = 0; hh < 2; ++hh) {
        float4 sv = *(const float4*)(csrow + 8 * lane + 4 * hh);
        float4 gv = *(const float4*)(cgrow + 8 * lane + 4 * hh);
        float4 w4 = *(const float4*)(wh + 8 * lane + 4 * hh);
        p = fmaf(w4.x, tanh_ps(sv.x + gv.x), p);
        p = fmaf(w4.y, tanh_ps(sv.y + gv.y), p);
        p = fmaf(w4.z, tanh_ps(sv.z + gv.z), p);
        p = fmaf(w4.w, tanh_ps(sv.w + gv.w), p);
    }
    #pragma unroll
    for (int off = 32; off; off >>= 1) p += __shfl_xor(p, off, 64);
    const float se = p;

    // ---- softmax over k (sum the two a-partials) ----
    const float* zrow0 = z_part + ((size_t)b * TDIM + t) * KDIM;
    const float* zrow1 = zrow0 + ZT_N;
    float z0 = zrow0[lane]       + zrow1[lane];
    float z1 = zrow0[lane + 64]  + zrow1[lane + 64];
    float z2 = zrow0[lane + 128] + zrow1[lane + 128];
    float z3 = (lane < 4) ? (zrow0[lane + 192] + zrow1[lane + 192]) : -INFINITY;

    float m = fmaxf(fmaxf(z0, z1), fmaxf(z2, z3));
    #pragma unroll
    for (int off = 32; off; off >>= 1) m = fmaxf(m, __shfl_xor(m, off, 64));

    float e0 = __expf(z0 - m), e1 = __expf(z1 - m);
    float e2 = __expf(z2 - m), e3 = (lane < 4) ? __expf(z3 - m) : 0.0f;
    float s = e0 + e1 + e2 + e3;
    #pragma unroll
    for (int off = 32; off; off >>= 1) s += __shfl_xor(s, off, 64);

    float invS = 1.0f / s;
    float a0 = e0 * invS, a1 = e1 * invS, a2 = e2 * invS, a3 = e3 * invS;

    alpha_s[wave][lane] = a0;
    alpha_s[wave][lane + 64] = a1;
    alpha_s[wave][lane + 128] = a2;
    if (lane < 4) alpha_s[wave][lane + 192] = a3;
    if (hs == 0) {
        float* arow = out_alpha + ((size_t)b * TDIM + t) * KDIM;
        arow[lane] = a0;
        arow[lane + 64] = a1;
        arow[lane + 128] = a2;
        if (lane < 4) arow[lane + 192] = a3;
    }

    float m2 = fmaxf(m, se);
    float eext = __expf(se - m2);
    float S2 = s * __expf(m - m2) + eext;
    float beta = eext / S2;
    if (lane == 0) {
        beta_s[wave] = beta;
        if (hs == 0) out_beta[b * TDIM + t] = beta;
    }
    __syncthreads();

    // ---- c_t for 4 t's: thread covers one h ----
    const float* attb = att + (size_t)b * KDIM * HDIM;
    float acc[4] = {};
    #pragma unroll 8
    for (int k = 0; k < KDIM; ++k) {
        float av = attb[(size_t)k * HDIM + h];
        #pragma unroll
        for (int w = 0; w < 4; ++w)
            acc[w] = fmaf(alpha_s[w][k], av, acc[w]);
    }

    #pragma unroll
    for (int w = 0; w < 4; ++w) {
        int tt = tg * 4 + w;
        float bt = beta_s[w];
        float om = 1.0f - bt;
        size_t o = ((size_t)b * TDIM + tt) * HDIM;
        out_chat[o + h] = fmaf(bt, sen[o + h], om * acc[w]);
    }
}

// ---------------------------------------------------------------------------
// fallback fp32 tiled GEMM (only if workspace too small for bf16 path);
// writes C pre-scaled by ZSC.
// ---------------------------------------------------------------------------
__global__ __launch_bounds__(256) void gemm_f32(const float* __restrict__ Amat,
                                                const float* __restrict__ Bmat,
                                                float* __restrict__ Cmat) {
    __shared__ float As[16][64 + 4];
    __shared__ float Bs[16][64];
    const int tid = threadIdx.x;
    const int tx = tid & 15;
    const int ty = tid >> 4;
    const int row0 = blockIdx.x * 64;
    const int col0 = blockIdx.y * 64;
    float acc[4][4] = {};
    for (int k0 = 0; k0 < HDIM; k0 += 16) {
        #pragma unroll
        for (int i = 0; i < 4; ++i) {
            int idx = tid + i * 256;
            As[idx & 15][idx >> 4] = Amat[(size_t)(row0 + (idx >> 4)) * HDIM + k0 + (idx & 15)];
        }
        #pragma unroll
        for (int i = 0; i < 4; ++i) {
            int idx = tid + i * 256;
            Bs[idx >> 6][idx & 63] = Bmat[(size_t)(k0 + (idx >> 6)) * ADIM + col0 + (idx & 63)];
        }
        __syncthreads();
        #pragma unroll
        for (int k = 0; k < 16; ++k) {
            float4 a4 = *(const float4*)&As[k][ty * 4];
            float4 b4 = *(const float4*)&Bs[k][tx * 4];
            float a[4] = {a4.x, a4.y, a4.z, a4.w};
            float b[4] = {b4.x, b4.y, b4.z, b4.w};
            #pragma unroll
            for (int i = 0; i < 4; ++i)
                #pragma unroll
                for (int j = 0; j < 4; ++j)
                    acc[i][j] += a[i] * b[j];
        }
        __syncthreads();
    }
    #pragma unroll
    for (int i = 0; i < 4; ++i) {
        size_t r = (size_t)(row0 + ty * 4 + i) * ADIM + col0 + tx * 4;
        #pragma unroll
        for (int j = 0; j < 4; ++j) Cmat[r + j] = acc[i][j] * ZSC;
    }
}

// z-partial fallback helper: writes the second partial as zero when the fp32
// fallback path computed full z into partial 0. (Not used in main path.)
__global__ __launch_bounds__(256) void zero_fill(float* __restrict__ p, int n) {
    int i = blockIdx.x * 256 + threadIdx.x;
    if (i < n) p[i] = 0.f;
}

// ---------------------------------------------------------------------------
extern "C" void kernel_launch(void* const* d_in, const int* in_sizes, int n_in,
                              void* d_out, int out_size, void* d_ws, size_t ws_size,
                              hipStream_t stream) {
    const float* att = (const float*)d_in[0];
    const float* hid = (const float*)d_in[1];
    const float* sen = (const float*)d_in[2];
    const float* Wv  = (const float*)d_in[3];
    const float* Wg  = (const float*)d_in[4];
    const float* Ws  = (const float*)d_in[5];
    const float* wh  = (const float*)d_in[6];

    float* out = (float*)d_out;
    float* out_chat  = out;
    float* out_alpha = out + 524288;
    float* out_beta  = out + 524288 + 200704;

    char* wsb = (char*)d_ws;
    const size_t C_BYTES  = (size_t)MROWS * 512 * 4;   // 17,039,360
    const size_t ZT_BYTES = (size_t)2 * ZT_N * 4;      // two partials
    const size_t BT_BYTES = (size_t)3 * 512 * 512 * 2; // 1,572,864
    const size_t need = C_BYTES + ZT_BYTES + 2 * BT_BYTES;

    float* C  = (float*)wsb;
    float* cv = C;                         // rows [0, 6272)
    float* cg = C + 6272 * 512;            // rows [6272, 7296)
    float* cs = C + 7296 * 512;            // rows [7296, 8320)
    float* zt = (float*)(wsb + C_BYTES);   // 2 x ZT_N partials

    if (ws_size >= need) {
        __hip_bfloat16* bthi = (__hip_bfloat16*)(wsb + C_BYTES + ZT_BYTES);
        __hip_bfloat16* btlo = bthi + (size_t)3 * 512 * 512;

        convB<<<192, 256, 0, stream>>>(Wv, Wg, Ws, bthi, btlo);
        gemm_bf16x3<<<dim3(130, 4), 256, 0, stream>>>(att, hid, sen, bthi, btlo, C);
    } else {
        gemm_f32<<<dim3(98, 8), 256, 0, stream>>>(att, Wv, cv);
        gemm_f32<<<dim3(16, 8), 256, 0, stream>>>(hid, Wg, cg);
        gemm_f32<<<dim3(16, 8), 256, 0, stream>>>(sen, Ws, cs);
    }

    z_kernel<<<dim3(25, 32, 2), 256, 0, stream>>>(cv, cg, wh, zt);

    out_kernel<<<dim3(8, 32, 2), 256, 0, stream>>>(zt, cs, cg, wh, att, sen,
                                                   out_chat, out_alpha, out_beta);
}